// Round 1
// baseline (504.671 us; speedup 1.0000x reference)
//
#include <hip/hip_runtime.h>
#include <hip/hip_bf16.h>

// BCE: mean over 67.1M elements of -(target ? log(p) : log(1-p)).
// Memory-bound streaming reduction: 537 MB in -> scalar out.
// Structure: vectorized grid-stride partial sums -> per-block double partial
// in d_ws (deterministic, no atomics) -> tiny final-reduce kernel.

#define BLOCKS 2048
#define THREADS 256

__global__ __launch_bounds__(THREADS) void bce_partial_kernel(
    const float* __restrict__ p, const int* __restrict__ t,
    double* __restrict__ partial, long long nvec, long long n) {
  long long tid = (long long)blockIdx.x * blockDim.x + threadIdx.x;
  long long stride = (long long)gridDim.x * blockDim.x;

  float sum = 0.0f;
  const float4* p4 = reinterpret_cast<const float4*>(p);
  const int4* t4 = reinterpret_cast<const int4*>(t);
  for (long long i = tid; i < nvec; i += stride) {
    float4 pv = p4[i];
    int4 tv = t4[i];
    // one transcendental per element; argument select is branch-free
    sum += __logf(tv.x ? pv.x : 1.0f - pv.x);
    sum += __logf(tv.y ? pv.y : 1.0f - pv.y);
    sum += __logf(tv.z ? pv.z : 1.0f - pv.z);
    sum += __logf(tv.w ? pv.w : 1.0f - pv.w);
  }
  // scalar tail (n not divisible by 4) — handled by first threads
  long long tail_start = nvec * 4;
  long long tail_n = n - tail_start;
  if (tid < tail_n) {
    long long i = tail_start + tid;
    sum += __logf(t[i] ? p[i] : 1.0f - p[i]);
  }

  // wave64 reduction (f32 is plenty for ~64*128 bounded terms)
  for (int off = 32; off > 0; off >>= 1) sum += __shfl_down(sum, off);

  __shared__ float wsum[THREADS / 64];
  int lane = threadIdx.x & 63;
  int wave = threadIdx.x >> 6;
  if (lane == 0) wsum[wave] = sum;
  __syncthreads();
  if (threadIdx.x == 0) {
    double bsum = 0.0;
    #pragma unroll
    for (int w = 0; w < THREADS / 64; ++w) bsum += (double)wsum[w];
    partial[blockIdx.x] = bsum;  // every slot written every launch (ws is poisoned)
  }
}

__global__ __launch_bounds__(256) void bce_final_kernel(
    const double* __restrict__ partial, int nparts, float* __restrict__ out,
    double inv_n) {
  double s = 0.0;
  for (int i = threadIdx.x; i < nparts; i += blockDim.x) s += partial[i];
  for (int off = 32; off > 0; off >>= 1) s += __shfl_down(s, off);
  __shared__ double wsum[4];
  int lane = threadIdx.x & 63;
  int wave = threadIdx.x >> 6;
  if (lane == 0) wsum[wave] = s;
  __syncthreads();
  if (threadIdx.x == 0) {
    double tot = wsum[0] + wsum[1] + wsum[2] + wsum[3];
    out[0] = (float)(-tot * inv_n);
  }
}

extern "C" void kernel_launch(void* const* d_in, const int* in_sizes, int n_in,
                              void* d_out, int out_size, void* d_ws, size_t ws_size,
                              hipStream_t stream) {
  const float* p = (const float*)d_in[0];
  const int* t = (const int*)d_in[1];
  float* out = (float*)d_out;
  double* partial = (double*)d_ws;

  long long n = (long long)in_sizes[0];
  long long nvec = n / 4;

  long long want = (nvec + THREADS - 1) / THREADS;
  int blocks = (int)(want < BLOCKS ? (want > 0 ? want : 1) : BLOCKS);

  bce_partial_kernel<<<blocks, THREADS, 0, stream>>>(p, t, partial, nvec, n);
  bce_final_kernel<<<1, 256, 0, stream>>>(partial, blocks, out, 1.0 / (double)n);
}

// Round 2
// 482.507 us; speedup vs baseline: 1.0459x; 1.0459x over previous
//
#include <hip/hip_runtime.h>
#include <hip/hip_bf16.h>

// BCE: mean over 67.1M elements of -(target ? log(p) : log(1-p)).
// Memory-bound streaming reduction: 537 MB in -> scalar out. Floor ~85us.
// R2 changes vs R1: nontemporal (streaming) loads, 2x unroll with
// independent accumulators for more outstanding loads per wave.

#define BLOCKS 2048
#define THREADS 256

typedef float  f32x4 __attribute__((ext_vector_type(4)));
typedef int    i32x4 __attribute__((ext_vector_type(4)));

__global__ __launch_bounds__(THREADS) void bce_partial_kernel(
    const float* __restrict__ p, const int* __restrict__ t,
    double* __restrict__ partial, long long nvec, long long n) {
  long long tid = (long long)blockIdx.x * blockDim.x + threadIdx.x;
  long long stride = (long long)gridDim.x * blockDim.x;

  const f32x4* p4 = reinterpret_cast<const f32x4*>(p);
  const i32x4* t4 = reinterpret_cast<const i32x4*>(t);

  float s0 = 0.0f, s1 = 0.0f;
  long long i = tid;
  // 2x-unrolled main loop: 4 loads (64 B) in flight per iteration,
  // two independent accumulator chains.
  for (; i + stride < nvec; i += 2 * stride) {
    f32x4 pa = __builtin_nontemporal_load(&p4[i]);
    i32x4 ta = __builtin_nontemporal_load(&t4[i]);
    f32x4 pb = __builtin_nontemporal_load(&p4[i + stride]);
    i32x4 tb = __builtin_nontemporal_load(&t4[i + stride]);
    s0 += __logf(ta.x ? pa.x : 1.0f - pa.x);
    s0 += __logf(ta.y ? pa.y : 1.0f - pa.y);
    s0 += __logf(ta.z ? pa.z : 1.0f - pa.z);
    s0 += __logf(ta.w ? pa.w : 1.0f - pa.w);
    s1 += __logf(tb.x ? pb.x : 1.0f - pb.x);
    s1 += __logf(tb.y ? pb.y : 1.0f - pb.y);
    s1 += __logf(tb.z ? pb.z : 1.0f - pb.z);
    s1 += __logf(tb.w ? pb.w : 1.0f - pb.w);
  }
  if (i < nvec) {
    f32x4 pa = __builtin_nontemporal_load(&p4[i]);
    i32x4 ta = __builtin_nontemporal_load(&t4[i]);
    s0 += __logf(ta.x ? pa.x : 1.0f - pa.x);
    s0 += __logf(ta.y ? pa.y : 1.0f - pa.y);
    s0 += __logf(ta.z ? pa.z : 1.0f - pa.z);
    s0 += __logf(ta.w ? pa.w : 1.0f - pa.w);
  }
  float sum = s0 + s1;

  // scalar tail (n not divisible by 4) — handled by first threads
  long long tail_start = nvec * 4;
  long long tail_n = n - tail_start;
  if (tid < tail_n) {
    long long j = tail_start + tid;
    sum += __logf(t[j] ? p[j] : 1.0f - p[j]);
  }

  // wave64 reduction (f32 fine: <=128 bounded terms per lane)
  for (int off = 32; off > 0; off >>= 1) sum += __shfl_down(sum, off);

  __shared__ float wsum[THREADS / 64];
  int lane = threadIdx.x & 63;
  int wave = threadIdx.x >> 6;
  if (lane == 0) wsum[wave] = sum;
  __syncthreads();
  if (threadIdx.x == 0) {
    double bsum = 0.0;
    #pragma unroll
    for (int w = 0; w < THREADS / 64; ++w) bsum += (double)wsum[w];
    partial[blockIdx.x] = bsum;  // every slot written every launch
  }
}

__global__ __launch_bounds__(256) void bce_final_kernel(
    const double* __restrict__ partial, int nparts, float* __restrict__ out,
    double inv_n) {
  double s = 0.0;
  for (int i = threadIdx.x; i < nparts; i += blockDim.x) s += partial[i];
  for (int off = 32; off > 0; off >>= 1) s += __shfl_down(s, off);
  __shared__ double wsum[4];
  int lane = threadIdx.x & 63;
  int wave = threadIdx.x >> 6;
  if (lane == 0) wsum[wave] = s;
  __syncthreads();
  if (threadIdx.x == 0) {
    double tot = wsum[0] + wsum[1] + wsum[2] + wsum[3];
    out[0] = (float)(-tot * inv_n);
  }
}

extern "C" void kernel_launch(void* const* d_in, const int* in_sizes, int n_in,
                              void* d_out, int out_size, void* d_ws, size_t ws_size,
                              hipStream_t stream) {
  const float* p = (const float*)d_in[0];
  const int* t = (const int*)d_in[1];
  float* out = (float*)d_out;
  double* partial = (double*)d_ws;

  long long n = (long long)in_sizes[0];
  long long nvec = n / 4;

  long long want = (nvec + THREADS - 1) / THREADS;
  int blocks = (int)(want < BLOCKS ? (want > 0 ? want : 1) : BLOCKS);

  bce_partial_kernel<<<blocks, THREADS, 0, stream>>>(p, t, partial, nvec, n);
  bce_final_kernel<<<1, 256, 0, stream>>>(partial, blocks, out, 1.0 / (double)n);
}